// Round 1
// baseline (2600.736 us; speedup 1.0000x reference)
//
#include <hip/hip_runtime.h>

// Problem constants (from reference): N_NODES=500000, N_EDGES=16000000,
// V_DIM=2, E_DIM=3. MLP: 5 -> 50 (relu) -> 20 (relu) -> 1.

__global__ __launch_bounds__(256) void scatter_add_kernel(
    const int* __restrict__ tgt,      // edge_index row 1 (targets), int32
    const float* __restrict__ eattr,  // [E,3]
    float* __restrict__ agg,          // [N,3], pre-zeroed
    int n_edges) {
  int t = blockIdx.x * blockDim.x + threadIdx.x;
  int e0 = t * 4;
  if (e0 >= n_edges) return;
  if (e0 + 4 <= n_edges) {
    // Fully vectorized: 16B-aligned loads (t*16 B for tgt, t*48 B for eattr)
    int4 d4 = *(const int4*)(tgt + e0);
    const float4* ea = (const float4*)(eattr + (size_t)e0 * 3);
    float4 a = ea[0];
    float4 b = ea[1];
    float4 c = ea[2];
    atomicAdd(&agg[d4.x * 3 + 0], a.x);
    atomicAdd(&agg[d4.x * 3 + 1], a.y);
    atomicAdd(&agg[d4.x * 3 + 2], a.z);
    atomicAdd(&agg[d4.y * 3 + 0], a.w);
    atomicAdd(&agg[d4.y * 3 + 1], b.x);
    atomicAdd(&agg[d4.y * 3 + 2], b.y);
    atomicAdd(&agg[d4.z * 3 + 0], b.z);
    atomicAdd(&agg[d4.z * 3 + 1], b.w);
    atomicAdd(&agg[d4.z * 3 + 2], c.x);
    atomicAdd(&agg[d4.w * 3 + 0], c.y);
    atomicAdd(&agg[d4.w * 3 + 1], c.z);
    atomicAdd(&agg[d4.w * 3 + 2], c.w);
  } else {
    for (int e = e0; e < n_edges; ++e) {
      int d = tgt[e];
      atomicAdd(&agg[d * 3 + 0], eattr[(size_t)e * 3 + 0]);
      atomicAdd(&agg[d * 3 + 1], eattr[(size_t)e * 3 + 1]);
      atomicAdd(&agg[d * 3 + 2], eattr[(size_t)e * 3 + 2]);
    }
  }
}

__global__ __launch_bounds__(256) void mlp_kernel(
    const float* __restrict__ va,   // [N,2]
    const float* __restrict__ agg,  // [N,3]
    const float* __restrict__ W1, const float* __restrict__ b1,  // [50,5],[50]
    const float* __restrict__ W2, const float* __restrict__ b2,  // [20,50],[20]
    const float* __restrict__ W3, const float* __restrict__ b3,  // [1,20],[1]
    float* __restrict__ out,        // [N,1]
    int n) {
  int i = blockIdx.x * blockDim.x + threadIdx.x;
  if (i >= n) return;

  float x[5];
  float2 v = ((const float2*)va)[i];
  x[0] = v.x;
  x[1] = v.y;
  x[2] = agg[i * 3 + 0];
  x[3] = agg[i * 3 + 1];
  x[4] = agg[i * 3 + 2];

  // Layer 1: 5 -> 50, relu. Weight addresses are wave-uniform -> s_load.
  float h1[50];
#pragma unroll
  for (int j = 0; j < 50; ++j) {
    float s = b1[j];
#pragma unroll
    for (int k = 0; k < 5; ++k) s = fmaf(W1[j * 5 + k], x[k], s);
    h1[j] = fmaxf(s, 0.0f);
  }

  // Layer 2: 50 -> 20, relu.
  float h2[20];
  for (int j = 0; j < 20; ++j) {
    float s = b2[j];
#pragma unroll
    for (int k = 0; k < 50; ++k) s = fmaf(W2[j * 50 + k], h1[k], s);
    h2[j] = fmaxf(s, 0.0f);
  }

  // Layer 3: 20 -> 1.
  float s = b3[0];
#pragma unroll
  for (int k = 0; k < 20; ++k) s = fmaf(W3[k], h2[k], s);
  out[i] = s;
}

extern "C" void kernel_launch(void* const* d_in, const int* in_sizes, int n_in,
                              void* d_out, int out_size, void* d_ws, size_t ws_size,
                              hipStream_t stream) {
  const float* vertex_attr = (const float*)d_in[0];
  const int* edge_index = (const int*)d_in[1];  // [2, E] int32
  const float* edge_attr = (const float*)d_in[2];
  const float* W1 = (const float*)d_in[3];
  const float* b1 = (const float*)d_in[4];
  const float* W2 = (const float*)d_in[5];
  const float* b2 = (const float*)d_in[6];
  const float* W3 = (const float*)d_in[7];
  const float* b3 = (const float*)d_in[8];
  float* out = (float*)d_out;

  const int n_nodes = in_sizes[0] / 2;   // V_DIM = 2
  const int n_edges = in_sizes[2] / 3;   // E_DIM = 3
  const int* tgt = edge_index + n_edges; // row 1 = targets

  float* agg = (float*)d_ws;  // [n_nodes, 3] accumulator
  hipMemsetAsync(agg, 0, (size_t)n_nodes * 3 * sizeof(float), stream);

  {
    int threads = (n_edges + 3) / 4;
    int blocks = (threads + 255) / 256;
    scatter_add_kernel<<<blocks, 256, 0, stream>>>(tgt, edge_attr, agg, n_edges);
  }
  {
    int blocks = (n_nodes + 255) / 256;
    mlp_kernel<<<blocks, 256, 0, stream>>>(vertex_attr, agg, W1, b1, W2, b2,
                                           W3, b3, out, n_nodes);
  }
}